// Round 3
// baseline (536.134 us; speedup 1.0000x reference)
//
#include <hip/hip_runtime.h>

// Problem constants (fixed by the reference setup)
constexpr int N_IN  = 50000;
constexpr int C     = 64;
constexpr int T     = 8;
constexpr int E     = 800000;
constexpr int N_OUT = 50000;
constexpr int F     = 64;

// ---------------------------------------------------------------------------
// Workspace layout (bytes). Proven available: >= 102,400,000 B (round 2).
//   proj  : bf16 [N_IN][T][F]      51,200,000
//   cnt   : int  [N_OUT+1]            200,004 (doubles as start[] after scan)
//   cursor: int  [N_OUT]              200,000
//   bsum  : int  [256]                  1,024
//   rec   : int2 [E]                6,400,000   {idx_in, e}
// ---------------------------------------------------------------------------
constexpr size_t OFF_PROJ = 0;
constexpr size_t OFF_CNT  = 51200000;             // 4-aligned
constexpr size_t OFF_CUR  = OFF_CNT + 200064;
constexpr size_t OFF_BSUM = OFF_CUR + 200064;
constexpr size_t OFF_REC  = OFF_BSUM + 1024;      // 8-aligned

__device__ inline unsigned short f2bf(float x) {  // fp32 -> bf16, RNE
    unsigned int u = __float_as_uint(x);
    unsigned int r = (u + 0x7FFFu + ((u >> 16) & 1u)) >> 16;
    return (unsigned short)r;
}
__device__ inline float bf2f(unsigned short u) {
    return __uint_as_float(((unsigned int)u) << 16);
}

// ---------------------------------------------------------------------------
// K1: proj[i, t, f] = sum_c nf[i,c] * K[t,c,f]   (bf16 output)
//   grid = (196, T), block = 256; thread = one (i, t), all 64 f.
// ---------------------------------------------------------------------------
__global__ __launch_bounds__(256) void project_kernel(const float* __restrict__ nf,
                                                      const float* __restrict__ Kmat,
                                                      unsigned short* __restrict__ proj) {
    __shared__ float Ks[C * F];  // 16 KB

    const int t = blockIdx.y;
    const int i = blockIdx.x * 256 + threadIdx.x;

    const float4* Kg  = (const float4*)(Kmat + (size_t)t * C * F);
    float4*       Ks4 = (float4*)Ks;
#pragma unroll
    for (int k = 0; k < 4; ++k) Ks4[k * 256 + threadIdx.x] = Kg[k * 256 + threadIdx.x];
    __syncthreads();

    if (i >= N_IN) return;

    float reg[C];
    const float4* row = (const float4*)(nf + (size_t)i * C);
#pragma unroll
    for (int k = 0; k < 16; ++k) {
        float4 v = row[k];
        reg[4 * k + 0] = v.x; reg[4 * k + 1] = v.y;
        reg[4 * k + 2] = v.z; reg[4 * k + 3] = v.w;
    }

    unsigned int w[32];  // 64 bf16 packed
#pragma unroll
    for (int fg = 0; fg < 16; ++fg) {
        float4 acc = {0.f, 0.f, 0.f, 0.f};
#pragma unroll
        for (int c = 0; c < C; ++c) {
            float4 kv = *(const float4*)(Ks + c * F + fg * 4);  // broadcast b128
            acc.x += reg[c] * kv.x;
            acc.y += reg[c] * kv.y;
            acc.z += reg[c] * kv.z;
            acc.w += reg[c] * kv.w;
        }
        w[2 * fg + 0] = (unsigned int)f2bf(acc.x) | ((unsigned int)f2bf(acc.y) << 16);
        w[2 * fg + 1] = (unsigned int)f2bf(acc.z) | ((unsigned int)f2bf(acc.w) << 16);
    }

    uint4* dst = (uint4*)(proj + (size_t)i * (T * F) + (size_t)t * F);
#pragma unroll
    for (int k = 0; k < 8; ++k)
        dst[k] = make_uint4(w[4 * k], w[4 * k + 1], w[4 * k + 2], w[4 * k + 3]);
}

// ---------------------------------------------------------------------------
// Sort pass 1: histogram of idx_out
// ---------------------------------------------------------------------------
__global__ __launch_bounds__(256) void hist_kernel(const int* __restrict__ idx,
                                                   int* __restrict__ cnt) {
    int e = blockIdx.x * 256 + threadIdx.x;
    if (e < E) atomicAdd(&cnt[idx[2 * e]], 1);
}

// Block-level inclusive scan helper (256 elements in LDS)
__device__ inline int block_incl_scan(int v, int* sh) {
    const int tid = threadIdx.x;
    sh[tid] = v;
    __syncthreads();
#pragma unroll
    for (int off = 1; off < 256; off <<= 1) {
        int x = 0;
        if (tid >= off) x = sh[tid - off];
        __syncthreads();
        if (tid >= off) sh[tid] += x;
        __syncthreads();
    }
    return sh[tid];
}

// Sort pass 2a: per-chunk exclusive scan (in place), chunk totals -> bsum
__global__ __launch_bounds__(256) void scanA_kernel(int* __restrict__ cnt,
                                                    int* __restrict__ bsum) {
    __shared__ int sh[256];
    int g = blockIdx.x * 256 + threadIdx.x;
    int v = (g < N_OUT) ? cnt[g] : 0;
    int incl = block_incl_scan(v, sh);
    if (g < N_OUT) cnt[g] = incl - v;
    if (threadIdx.x == 255) bsum[blockIdx.x] = incl;
}

// Sort pass 2b: exclusive scan of 196 chunk totals (single block)
__global__ __launch_bounds__(256) void scanB_kernel(int* __restrict__ bsum, int nchunks) {
    __shared__ int sh[256];
    int tid = threadIdx.x;
    int v = (tid < nchunks) ? bsum[tid] : 0;
    int incl = block_incl_scan(v, sh);
    if (tid < nchunks) bsum[tid] = incl - v;
}

// Sort pass 2c: add chunk offsets; init cursor; set start[N_OUT] = E
__global__ __launch_bounds__(256) void scanC_kernel(int* __restrict__ cnt,
                                                    const int* __restrict__ bsum,
                                                    int* __restrict__ cursor) {
    int g = blockIdx.x * 256 + threadIdx.x;
    if (g < N_OUT) {
        int s = cnt[g] + bsum[blockIdx.x];
        cnt[g] = s;
        cursor[g] = s;
    }
    if (blockIdx.x == 0 && threadIdx.x == 0) cnt[N_OUT] = E;
}

// Sort pass 3: scatter edge records into segment order
__global__ __launch_bounds__(256) void scatter_kernel(const int* __restrict__ idx,
                                                      int* __restrict__ cursor,
                                                      int2* __restrict__ rec) {
    int e = blockIdx.x * 256 + threadIdx.x;
    if (e >= E) return;
    int o = idx[2 * e];
    int i = idx[2 * e + 1];
    int pos = atomicAdd(&cursor[o], 1);
    rec[pos] = make_int2(i, e);
}

// ---------------------------------------------------------------------------
// K2: one wave per output node o; lane = f.
//   out[o,f] = bias[f] + sum_{p in segment(o)} sum_t ef[t,e_p] * proj[i_p,t,f]
//   No atomics: single coalesced 256 B store per node.
// ---------------------------------------------------------------------------
__global__ __launch_bounds__(256) void aggregate_kernel(const float* __restrict__ ef,
                                                        const unsigned short* __restrict__ proj,
                                                        const int* __restrict__ start,
                                                        const int2* __restrict__ rec,
                                                        const float* __restrict__ bias,
                                                        float* __restrict__ out) {
    const int o    = blockIdx.x * 4 + (threadIdx.x >> 6);
    const int lane = threadIdx.x & 63;
    if (o >= N_OUT) return;

    const int s    = __builtin_amdgcn_readfirstlane(start[o]);
    const int send = __builtin_amdgcn_readfirstlane(start[o + 1]);

    float acc = 0.f;
    for (int p = s; p < send; ++p) {
        int2 r = rec[p];  // all lanes same address -> 1 txn
        const int iu = __builtin_amdgcn_readfirstlane(r.x);
        const int eu = __builtin_amdgcn_readfirstlane(r.y);

        const unsigned short* pb = proj + (size_t)iu * (T * F) + lane;
#pragma unroll
        for (int t = 0; t < T; ++t) {
            float w = ef[t * E + eu];        // scalar (SGPR) load
            acc += w * bf2f(pb[t * F]);      // 128 B coalesced gather per t
        }
    }

    out[(size_t)o * F + lane] = acc + bias[lane];
}

// ---------------------------------------------------------------------------
extern "C" void kernel_launch(void* const* d_in, const int* in_sizes, int n_in,
                              void* d_out, int out_size, void* d_ws, size_t ws_size,
                              hipStream_t stream) {
    const float* nf   = (const float*)d_in[0];  // (N_IN, C)
    const float* ef   = (const float*)d_in[1];  // (T, E)
    const int*   idx  = (const int*)d_in[2];    // (E, 2) int32 on device
    const float* Kmat = (const float*)d_in[3];  // (T, C, F)
    const float* bias = (const float*)d_in[4];  // (F,)
    float*       out  = (float*)d_out;          // (N_OUT, F)

    char* ws = (char*)d_ws;
    unsigned short* proj   = (unsigned short*)(ws + OFF_PROJ);
    int*            cnt    = (int*)(ws + OFF_CNT);   // becomes start[]
    int*            cursor = (int*)(ws + OFF_CUR);
    int*            bsum   = (int*)(ws + OFF_BSUM);
    int2*           rec    = (int2*)(ws + OFF_REC);

    const int nchunks = (N_OUT + 255) / 256;  // 196

    // K1: projection (fp32 -> bf16)
    dim3 pgrid((N_IN + 255) / 256, T);
    project_kernel<<<pgrid, 256, 0, stream>>>(nf, Kmat, proj);

    // Counting sort of edges by idx_out
    hipMemsetAsync(cnt, 0, (N_OUT + 1) * sizeof(int), stream);
    hist_kernel<<<(E + 255) / 256, 256, 0, stream>>>(idx, cnt);
    scanA_kernel<<<nchunks, 256, 0, stream>>>(cnt, bsum);
    scanB_kernel<<<1, 256, 0, stream>>>(bsum, nchunks);
    scanC_kernel<<<nchunks, 256, 0, stream>>>(cnt, bsum, cursor);
    scatter_kernel<<<(E + 255) / 256, 256, 0, stream>>>(idx, cursor, rec);

    // K2: segment aggregation, wave per output node, no atomics
    aggregate_kernel<<<(N_OUT + 3) / 4, 256, 0, stream>>>(ef, proj, cnt, rec, bias, out);
}

// Round 4
// 262.618 us; speedup vs baseline: 2.0415x; 2.0415x over previous
//
#include <hip/hip_runtime.h>

// Problem constants (fixed by the reference setup)
constexpr int N_IN  = 50000;
constexpr int C     = 64;
constexpr int T     = 8;
constexpr int E     = 800000;
constexpr int N_OUT = 50000;
constexpr int F     = 64;

// ---------------------------------------------------------------------------
// Workspace layout (bytes); total ~38.9 MB (ws >= 102.4 MB proven round 2)
// ---------------------------------------------------------------------------
constexpr size_t OFF_NFBF = 0;                       // bf16 [N_IN][64]     6.4 MB
constexpr size_t OFF_KT   = 6400000;                 // bf16 [64][512]      64 KB
constexpr size_t OFF_EFT  = OFF_KT + 65536;          // f32  [E][8]        25.6 MB
constexpr size_t OFF_CNT  = OFF_EFT + 25600000;      // int  [N_OUT+1]
constexpr size_t OFF_CUR  = OFF_CNT + 200064;        // int  [N_OUT]
constexpr size_t OFF_BSUM = OFF_CUR + 200064;        // int  [256]
constexpr size_t OFF_REC  = OFF_BSUM + 1024;         // int2 [E]            6.4 MB

typedef __attribute__((ext_vector_type(8))) short short8;
typedef __attribute__((ext_vector_type(4))) float f32x4;

__device__ inline unsigned short f2bf(float x) {  // fp32 -> bf16, RNE
    unsigned int u = __float_as_uint(x);
    unsigned int r = (u + 0x7FFFu + ((u >> 16) & 1u)) >> 16;
    return (unsigned short)r;
}
__device__ inline float bf2f(unsigned short u) {
    return __uint_as_float(((unsigned int)u) << 16);
}

// ---------------------------------------------------------------------------
// Prep A: nf (fp32) -> nf_bf (bf16), 4 floats/thread
// ---------------------------------------------------------------------------
__global__ __launch_bounds__(256) void nf_convert_kernel(const float* __restrict__ nf,
                                                         unsigned short* __restrict__ nf_bf) {
    int i = blockIdx.x * 256 + threadIdx.x;  // index in float4 units
    if (i >= N_IN * C / 4) return;
    float4 v = ((const float4*)nf)[i];
    unsigned int u0 = (unsigned int)f2bf(v.x) | ((unsigned int)f2bf(v.y) << 16);
    unsigned int u1 = (unsigned int)f2bf(v.z) | ((unsigned int)f2bf(v.w) << 16);
    ((uint2*)nf_bf)[i] = make_uint2(u0, u1);
}

// ---------------------------------------------------------------------------
// Prep B: K_T[f][t*64+c] = bf16(K[t][c][f])   (64 x 512 bf16 = 64 KB)
// ---------------------------------------------------------------------------
__global__ __launch_bounds__(256) void kt_kernel(const float* __restrict__ Kmat,
                                                 unsigned short* __restrict__ K_T) {
    for (int idx = blockIdx.x * 256 + threadIdx.x; idx < T * C * F; idx += gridDim.x * 256) {
        int f = idx & 63;
        int c = (idx >> 6) & 63;
        int t = idx >> 12;
        K_T[f * 512 + t * 64 + c] = f2bf(Kmat[idx]);
    }
}

// ---------------------------------------------------------------------------
// Prep C: ef_T[e][t] = ef[t][e]  (per-edge contiguous 32 B of weights)
// ---------------------------------------------------------------------------
__global__ __launch_bounds__(256) void eft_kernel(const float* __restrict__ ef,
                                                  float* __restrict__ ef_T) {
    int e = blockIdx.x * 256 + threadIdx.x;
    if (e >= E) return;
    float v[8];
#pragma unroll
    for (int t = 0; t < T; ++t) v[t] = ef[(size_t)t * E + e];  // coalesced per t
    float4* dst = (float4*)(ef_T + (size_t)e * 8);
    dst[0] = make_float4(v[0], v[1], v[2], v[3]);
    dst[1] = make_float4(v[4], v[5], v[6], v[7]);
}

// ---------------------------------------------------------------------------
// Counting sort of edges by idx_out (hist -> scan -> scatter)
// ---------------------------------------------------------------------------
__global__ __launch_bounds__(256) void hist_kernel(const int* __restrict__ idx,
                                                   int* __restrict__ cnt) {
    int e = blockIdx.x * 256 + threadIdx.x;
    if (e < E) atomicAdd(&cnt[idx[2 * e]], 1);
}

__device__ inline int block_incl_scan(int v, int* sh) {
    const int tid = threadIdx.x;
    sh[tid] = v;
    __syncthreads();
#pragma unroll
    for (int off = 1; off < 256; off <<= 1) {
        int x = 0;
        if (tid >= off) x = sh[tid - off];
        __syncthreads();
        if (tid >= off) sh[tid] += x;
        __syncthreads();
    }
    return sh[tid];
}

__global__ __launch_bounds__(256) void scanA_kernel(int* __restrict__ cnt,
                                                    int* __restrict__ bsum) {
    __shared__ int sh[256];
    int g = blockIdx.x * 256 + threadIdx.x;
    int v = (g < N_OUT) ? cnt[g] : 0;
    int incl = block_incl_scan(v, sh);
    if (g < N_OUT) cnt[g] = incl - v;
    if (threadIdx.x == 255) bsum[blockIdx.x] = incl;
}

__global__ __launch_bounds__(256) void scanB_kernel(int* __restrict__ bsum, int nchunks) {
    __shared__ int sh[256];
    int tid = threadIdx.x;
    int v = (tid < nchunks) ? bsum[tid] : 0;
    int incl = block_incl_scan(v, sh);
    if (tid < nchunks) bsum[tid] = incl - v;
}

__global__ __launch_bounds__(256) void scanC_kernel(int* __restrict__ cnt,
                                                    const int* __restrict__ bsum,
                                                    int* __restrict__ cursor) {
    int g = blockIdx.x * 256 + threadIdx.x;
    if (g < N_OUT) {
        int s = cnt[g] + bsum[blockIdx.x];
        cnt[g] = s;
        cursor[g] = s;
    }
    if (blockIdx.x == 0 && threadIdx.x == 0) cnt[N_OUT] = E;
}

__global__ __launch_bounds__(256) void scatter_kernel(const int* __restrict__ idx,
                                                      int* __restrict__ cursor,
                                                      int2* __restrict__ rec) {
    int e = blockIdx.x * 256 + threadIdx.x;
    if (e >= E) return;
    int o = idx[2 * e];
    int i = idx[2 * e + 1];
    int pos = atomicAdd(&cursor[o], 1);
    rec[pos] = make_int2(i, e);
}

// ---------------------------------------------------------------------------
// K2: block = 4 waves = 16 output nodes.
//  Phase 1 (per wave, 4 nodes sequentially, lane=c):
//     G[t,c] = sum_{edges} ef_T[e][t] * nf_bf[i][c]   (8 fp32 regs/lane)
//     -> bf16 -> A_lds[m][t*64+c]  (m = node-in-tile)
//  Phase 2 (per wave, one 16-col f-tile):
//     out_tile = A(16x512) @ K_T^T(512x64) via 16 chained mfma_f32_16x16x32_bf16
// ---------------------------------------------------------------------------
__global__ __launch_bounds__(256) void aggregate_kernel(const float* __restrict__ ef_T,
                                                        const unsigned short* __restrict__ nf_bf,
                                                        const unsigned short* __restrict__ K_T,
                                                        const int* __restrict__ start,
                                                        const int2* __restrict__ rec,
                                                        const float* __restrict__ bias,
                                                        float* __restrict__ out) {
    __shared__ unsigned short A_lds[16][520];  // +8 pad: kills 16-way bank conflict on b128 reads

    const int wave = threadIdx.x >> 6;
    const int lane = threadIdx.x & 63;
    const int node_base = blockIdx.x * 16;  // 50000 = 3125 * 16, exact

    // ---- Phase 1: segment aggregation ----
    for (int q = 0; q < 4; ++q) {
        const int m = wave * 4 + q;
        const int o = node_base + m;
        const int s0 = __builtin_amdgcn_readfirstlane(start[o]);
        const int s1 = __builtin_amdgcn_readfirstlane(start[o + 1]);

        float acc[8] = {0.f, 0.f, 0.f, 0.f, 0.f, 0.f, 0.f, 0.f};

        int p = s0;
        for (; p + 1 < s1; p += 2) {  // 2-edge unroll: both gathers in flight
            int2 r0 = rec[p];
            int2 r1 = rec[p + 1];
            float x0 = bf2f(nf_bf[(size_t)r0.x * 64 + lane]);
            float x1 = bf2f(nf_bf[(size_t)r1.x * 64 + lane]);
            const float* w0 = ef_T + (size_t)r0.y * 8;
            const float* w1 = ef_T + (size_t)r1.y * 8;
#pragma unroll
            for (int t = 0; t < T; ++t) acc[t] += w0[t] * x0;
#pragma unroll
            for (int t = 0; t < T; ++t) acc[t] += w1[t] * x1;
        }
        if (p < s1) {
            int2 r = rec[p];
            float x = bf2f(nf_bf[(size_t)r.x * 64 + lane]);
            const float* w = ef_T + (size_t)r.y * 8;
#pragma unroll
            for (int t = 0; t < T; ++t) acc[t] += w[t] * x;
        }

#pragma unroll
        for (int t = 0; t < T; ++t) A_lds[m][t * 64 + lane] = f2bf(acc[t]);
    }
    __syncthreads();

    // ---- Phase 2: MFMA epilogue; wave handles f-tile [wave*16, wave*16+16) ----
    const int mrow = lane & 15;       // A row (node-in-tile) / B col (f within tile)
    const int kb   = lane >> 4;       // k-block
    const int fcol = wave * 16 + mrow;

    f32x4 acc4 = {0.f, 0.f, 0.f, 0.f};
#pragma unroll
    for (int s = 0; s < 16; ++s) {
        const int k0 = s * 32 + kb * 8;
        short8 a = *(const short8*)&A_lds[mrow][k0];
        short8 b = *(const short8*)(K_T + (size_t)fcol * 512 + k0);  // B[k][n] = K_T[n][k]
        acc4 = __builtin_amdgcn_mfma_f32_16x16x32_bf16(a, b, acc4, 0, 0, 0);
    }

    // D layout (16x16x32): row m = (lane>>4)*4 + r, col n = lane&15
    const float bv = bias[fcol];
#pragma unroll
    for (int r = 0; r < 4; ++r) {
        const int m = kb * 4 + r;
        out[(size_t)(node_base + m) * F + fcol] = acc4[r] + bv;
    }
}

// ---------------------------------------------------------------------------
extern "C" void kernel_launch(void* const* d_in, const int* in_sizes, int n_in,
                              void* d_out, int out_size, void* d_ws, size_t ws_size,
                              hipStream_t stream) {
    const float* nf   = (const float*)d_in[0];  // (N_IN, C)
    const float* ef   = (const float*)d_in[1];  // (T, E)
    const int*   idx  = (const int*)d_in[2];    // (E, 2) int32 on device
    const float* Kmat = (const float*)d_in[3];  // (T, C, F)
    const float* bias = (const float*)d_in[4];  // (F,)
    float*       out  = (float*)d_out;          // (N_OUT, F)

    char* ws = (char*)d_ws;
    unsigned short* nf_bf  = (unsigned short*)(ws + OFF_NFBF);
    unsigned short* K_T    = (unsigned short*)(ws + OFF_KT);
    float*          ef_T   = (float*)(ws + OFF_EFT);
    int*            cnt    = (int*)(ws + OFF_CNT);  // becomes start[]
    int*            cursor = (int*)(ws + OFF_CUR);
    int*            bsum   = (int*)(ws + OFF_BSUM);
    int2*           rec    = (int2*)(ws + OFF_REC);

    const int nchunks = (N_OUT + 255) / 256;  // 196

    // Prep
    nf_convert_kernel<<<(N_IN * C / 4 + 255) / 256, 256, 0, stream>>>(nf, nf_bf);
    kt_kernel<<<32, 256, 0, stream>>>(Kmat, K_T);
    eft_kernel<<<(E + 255) / 256, 256, 0, stream>>>(ef, ef_T);

    // Counting sort of edges by idx_out
    hipMemsetAsync(cnt, 0, (N_OUT + 1) * sizeof(int), stream);
    hist_kernel<<<(E + 255) / 256, 256, 0, stream>>>(idx, cnt);
    scanA_kernel<<<nchunks, 256, 0, stream>>>(cnt, bsum);
    scanB_kernel<<<1, 256, 0, stream>>>(bsum, nchunks);
    scanC_kernel<<<nchunks, 256, 0, stream>>>(cnt, bsum, cursor);
    scatter_kernel<<<(E + 255) / 256, 256, 0, stream>>>(idx, cursor, rec);

    // Aggregate + MFMA epilogue
    aggregate_kernel<<<N_OUT / 16, 256, 0, stream>>>(ef_T, nf_bf, K_T, cnt, rec, bias, out);
}

// Round 5
// 233.859 us; speedup vs baseline: 2.2925x; 1.1230x over previous
//
#include <hip/hip_runtime.h>

// Problem constants (fixed by the reference setup)
constexpr int N_IN  = 50000;
constexpr int C     = 64;
constexpr int T     = 8;
constexpr int E     = 800000;
constexpr int N_OUT = 50000;
constexpr int F     = 64;

// ---------------------------------------------------------------------------
// Workspace layout (bytes); total ~35.6 MB (ws >= 102.4 MB proven round 2)
// ---------------------------------------------------------------------------
constexpr size_t OFF_NFBF = 0;                     // bf16 [N_IN][64]     6.4 MB
constexpr size_t OFF_KT   = 6400000;               // bf16 [64][512]      64 KB
constexpr size_t OFF_CNT  = OFF_KT + 65536;        // int  [N_OUT+1]      (-> start[])
constexpr size_t OFF_CUR  = OFF_CNT + 200064;      // int  [N_OUT]
constexpr size_t OFF_BSUM = OFF_CUR + 200064;      // int  [256]
constexpr size_t OFF_ISRT = OFF_BSUM + 1024;       // int  [E]            3.2 MB
constexpr size_t OFF_WSRT = OFF_ISRT + 3200000;    // f32  [E][8]        25.6 MB

typedef __attribute__((ext_vector_type(8))) short short8;
typedef __attribute__((ext_vector_type(4))) float f32x4;

__device__ inline unsigned short f2bf(float x) {  // fp32 -> bf16, RNE
    unsigned int u = __float_as_uint(x);
    unsigned int r = (u + 0x7FFFu + ((u >> 16) & 1u)) >> 16;
    return (unsigned short)r;
}
__device__ inline float bf2f(unsigned short u) {
    return __uint_as_float(((unsigned int)u) << 16);
}

// ---------------------------------------------------------------------------
// Fused prep: [0,3125) nf->bf16 | [3125,3157) K transpose | [3157,6282) hist
// ---------------------------------------------------------------------------
constexpr int NF_BLOCKS   = N_IN * C / 4 / 256;  // 3125 (exact)
constexpr int KT_BLOCKS   = 32;
constexpr int HIST_BLOCKS = E / 256;             // 3125 (exact)

__global__ __launch_bounds__(256) void prep_kernel(const float* __restrict__ nf,
                                                   const float* __restrict__ Kmat,
                                                   const int* __restrict__ idx,
                                                   unsigned short* __restrict__ nf_bf,
                                                   unsigned short* __restrict__ K_T,
                                                   int* __restrict__ cnt) {
    const int b   = blockIdx.x;
    const int tid = threadIdx.x;

    if (b < NF_BLOCKS) {
        int i = b * 256 + tid;  // float4 units; 800000 exact
        float4 v = ((const float4*)nf)[i];
        unsigned int u0 = (unsigned int)f2bf(v.x) | ((unsigned int)f2bf(v.y) << 16);
        unsigned int u1 = (unsigned int)f2bf(v.z) | ((unsigned int)f2bf(v.w) << 16);
        ((uint2*)nf_bf)[i] = make_uint2(u0, u1);
    } else if (b < NF_BLOCKS + KT_BLOCKS) {
        for (int k = (b - NF_BLOCKS) * 256 + tid; k < T * C * F; k += KT_BLOCKS * 256) {
            int f = k & 63;
            int c = (k >> 6) & 63;
            int t = k >> 12;
            K_T[f * 512 + t * 64 + c] = f2bf(Kmat[k]);
        }
    } else {
        int e = (b - NF_BLOCKS - KT_BLOCKS) * 256 + tid;  // 800000 exact
        atomicAdd(&cnt[idx[2 * e]], 1);
    }
}

// ---------------------------------------------------------------------------
// Scan pass A: per-256-chunk exclusive scan in place, chunk totals -> bsum
// ---------------------------------------------------------------------------
__global__ __launch_bounds__(256) void scanA_kernel(int* __restrict__ cnt,
                                                    int* __restrict__ bsum) {
    __shared__ int sh[256];
    const int tid = threadIdx.x;
    int g = blockIdx.x * 256 + tid;
    int v = (g < N_OUT) ? cnt[g] : 0;
    sh[tid] = v;
    __syncthreads();
#pragma unroll
    for (int off = 1; off < 256; off <<= 1) {
        int x = 0;
        if (tid >= off) x = sh[tid - off];
        __syncthreads();
        if (tid >= off) sh[tid] += x;
        __syncthreads();
    }
    int incl = sh[tid];
    if (g < N_OUT) cnt[g] = incl - v;
    if (tid == 255) bsum[blockIdx.x] = incl;
}

// ---------------------------------------------------------------------------
// Scan pass BC: each block adds sum(bsum[0..bi)) to its chunk; init cursor.
// ---------------------------------------------------------------------------
__global__ __launch_bounds__(256) void scanBC_kernel(int* __restrict__ cnt,
                                                     const int* __restrict__ bsum,
                                                     int* __restrict__ cursor) {
    __shared__ int sh[256];
    const int bi  = blockIdx.x;
    const int tid = threadIdx.x;
    sh[tid] = (tid < bi) ? bsum[tid] : 0;  // nchunks(196) < 256
    __syncthreads();
#pragma unroll
    for (int off = 128; off >= 1; off >>= 1) {
        if (tid < off) sh[tid] += sh[tid + off];
        __syncthreads();
    }
    const int offset = sh[0];
    int g = bi * 256 + tid;
    if (g < N_OUT) {
        int s = cnt[g] + offset;
        cnt[g] = s;
        cursor[g] = s;
    }
    if (bi == 0 && tid == 0) cnt[N_OUT] = E;
}

// ---------------------------------------------------------------------------
// Scatter: edges into segment order; also transposes the 8 edge weights into
// wsorted so aggregate's weight reads become sequential wave-uniform loads.
// ---------------------------------------------------------------------------
__global__ __launch_bounds__(256) void scatter_kernel(const int* __restrict__ idx,
                                                      const float* __restrict__ ef,
                                                      int* __restrict__ cursor,
                                                      int* __restrict__ isorted,
                                                      float* __restrict__ wsorted) {
    int e = blockIdx.x * 256 + threadIdx.x;  // 800000 exact
    int2 oi = ((const int2*)idx)[e];         // {idx_out, idx_in}
    int pos = atomicAdd(&cursor[oi.x], 1);
    isorted[pos] = oi.y;
    float w[8];
#pragma unroll
    for (int t = 0; t < T; ++t) w[t] = ef[(size_t)t * E + e];  // coalesced per t
    float4* dst = (float4*)(wsorted + (size_t)pos * 8);
    dst[0] = make_float4(w[0], w[1], w[2], w[3]);
    dst[1] = make_float4(w[4], w[5], w[6], w[7]);
}

// ---------------------------------------------------------------------------
// Aggregate: block = 4 waves = 16 output nodes.
//  Phase 1 (per wave, 4 nodes, lane=c):
//    preload 64 isorted entries coalesced, readlane-broadcast; 4-edge unroll
//    -> 4 independent 128 B nf gathers in flight; weights via uniform
//    sequential loads from wsorted (s_load path).
//    G[t,c] accumulated in 8 fp32 regs -> bf16 -> A_lds[m][t*64+c]
//  Phase 2 (per wave, one 16-col f-tile):
//    out_tile(16x64) = A(16x512) @ K_T^T via 16 chained mfma_f32_16x16x32_bf16
// ---------------------------------------------------------------------------
__global__ __launch_bounds__(256) void aggregate_kernel(const unsigned short* __restrict__ nf_bf,
                                                        const unsigned short* __restrict__ K_T,
                                                        const int* __restrict__ start,
                                                        const int* __restrict__ isorted,
                                                        const float* __restrict__ wsorted,
                                                        const float* __restrict__ bias,
                                                        float* __restrict__ out) {
    __shared__ unsigned short A_lds[16][520];  // +8 pad

    const int wave = threadIdx.x >> 6;
    const int lane = threadIdx.x & 63;
    const int node_base = blockIdx.x * 16;  // 50000 = 3125*16 exact

    // ---- Phase 1: segment aggregation ----
    for (int q = 0; q < 4; ++q) {
        const int m = wave * 4 + q;
        const int o = node_base + m;
        const int s0 = __builtin_amdgcn_readfirstlane(start[o]);
        const int s1 = __builtin_amdgcn_readfirstlane(start[o + 1]);

        float acc[8] = {0.f, 0.f, 0.f, 0.f, 0.f, 0.f, 0.f, 0.f};

        for (int base = s0; base < s1; base += 64) {
            const int cnt = min(64, s1 - base);
            // coalesced preload of this chunk's input-node ids
            int iv = (base + lane < s1) ? isorted[base + lane] : 0;

            int j = 0;
            for (; j + 4 <= cnt; j += 4) {
                const int i0 = __builtin_amdgcn_readlane(iv, j + 0);
                const int i1 = __builtin_amdgcn_readlane(iv, j + 1);
                const int i2 = __builtin_amdgcn_readlane(iv, j + 2);
                const int i3 = __builtin_amdgcn_readlane(iv, j + 3);
                // 4 independent 128 B gathers in flight
                float x0 = bf2f(nf_bf[(size_t)i0 * 64 + lane]);
                float x1 = bf2f(nf_bf[(size_t)i1 * 64 + lane]);
                float x2 = bf2f(nf_bf[(size_t)i2 * 64 + lane]);
                float x3 = bf2f(nf_bf[(size_t)i3 * 64 + lane]);
                // uniform sequential weight loads (scalar path)
                const float* wp = wsorted +
                    (size_t)__builtin_amdgcn_readfirstlane(base + j) * 8;
#pragma unroll
                for (int t = 0; t < T; ++t) {
                    acc[t] += wp[t] * x0;
                    acc[t] += wp[8 + t] * x1;
                    acc[t] += wp[16 + t] * x2;
                    acc[t] += wp[24 + t] * x3;
                }
            }
            for (; j < cnt; ++j) {
                const int i0 = __builtin_amdgcn_readlane(iv, j);
                float x0 = bf2f(nf_bf[(size_t)i0 * 64 + lane]);
                const float* wp = wsorted +
                    (size_t)__builtin_amdgcn_readfirstlane(base + j) * 8;
#pragma unroll
                for (int t = 0; t < T; ++t) acc[t] += wp[t] * x0;
            }
        }

#pragma unroll
        for (int t = 0; t < T; ++t) A_lds[m][t * 64 + lane] = f2bf(acc[t]);
    }
    __syncthreads();

    // ---- Phase 2: MFMA epilogue; wave handles f-tile [wave*16, wave*16+16) ----
    const int mrow = lane & 15;
    const int kb   = lane >> 4;
    const int fcol = wave * 16 + mrow;

    f32x4 acc4 = {0.f, 0.f, 0.f, 0.f};
#pragma unroll
    for (int s = 0; s < 16; ++s) {
        const int k0 = s * 32 + kb * 8;
        short8 a = *(const short8*)&A_lds[mrow][k0];
        short8 b = *(const short8*)(K_T + (size_t)fcol * 512 + k0);
        acc4 = __builtin_amdgcn_mfma_f32_16x16x32_bf16(a, b, acc4, 0, 0, 0);
    }

    const float bv = bias[fcol];
#pragma unroll
    for (int r = 0; r < 4; ++r) {
        const int m = kb * 4 + r;
        out[(size_t)(node_base + m) * F + fcol] = acc4[r] + bv;
    }
}

// ---------------------------------------------------------------------------
extern "C" void kernel_launch(void* const* d_in, const int* in_sizes, int n_in,
                              void* d_out, int out_size, void* d_ws, size_t ws_size,
                              hipStream_t stream) {
    const float* nf   = (const float*)d_in[0];  // (N_IN, C)
    const float* ef   = (const float*)d_in[1];  // (T, E)
    const int*   idx  = (const int*)d_in[2];    // (E, 2) int32 on device
    const float* Kmat = (const float*)d_in[3];  // (T, C, F)
    const float* bias = (const float*)d_in[4];  // (F,)
    float*       out  = (float*)d_out;          // (N_OUT, F)

    char* ws = (char*)d_ws;
    unsigned short* nf_bf   = (unsigned short*)(ws + OFF_NFBF);
    unsigned short* K_T     = (unsigned short*)(ws + OFF_KT);
    int*            cnt     = (int*)(ws + OFF_CNT);  // becomes start[]
    int*            cursor  = (int*)(ws + OFF_CUR);
    int*            bsum    = (int*)(ws + OFF_BSUM);
    int*            isorted = (int*)(ws + OFF_ISRT);
    float*          wsorted = (float*)(ws + OFF_WSRT);

    const int nchunks = (N_OUT + 255) / 256;  // 196

    hipMemsetAsync(cnt, 0, (N_OUT + 1) * sizeof(int), stream);
    prep_kernel<<<NF_BLOCKS + KT_BLOCKS + HIST_BLOCKS, 256, 0, stream>>>(
        nf, Kmat, idx, nf_bf, K_T, cnt);
    scanA_kernel<<<nchunks, 256, 0, stream>>>(cnt, bsum);
    scanBC_kernel<<<nchunks, 256, 0, stream>>>(cnt, bsum, cursor);
    scatter_kernel<<<E / 256, 256, 0, stream>>>(idx, ef, cursor, isorted, wsorted);
    aggregate_kernel<<<N_OUT / 16, 256, 0, stream>>>(
        nf_bf, K_T, cnt, isorted, wsorted, bias, out);
}